// Round 6
// baseline (1438.351 us; speedup 1.0000x reference)
//
#include <hip/hip_runtime.h>

typedef __bf16 bf16x8 __attribute__((ext_vector_type(8)));
typedef unsigned short us8 __attribute__((ext_vector_type(8)));
typedef float f32x4 __attribute__((ext_vector_type(4)));

#define NROW 32      // rows per workgroup (160 WGs x 32 = 5120)
#define A_STR 136    // ushort stride per A row
#define NSTEP 119

__device__ __forceinline__ unsigned short f2bf(float f){
  unsigned int x = __builtin_bit_cast(unsigned int, f);
  x += 0x7fffu + ((x >> 16) & 1u);          // RNE
  return (unsigned short)(x >> 16);
}
__device__ __forceinline__ float bf2f(unsigned short s){
  unsigned int x = ((unsigned int)s) << 16;
  return __builtin_bit_cast(float, x);
}
__device__ __forceinline__ float sigm(float x){ return 1.0f/(1.0f + __expf(-x)); }
__device__ __forceinline__ float tanh_(float x){ float e = __expf(2.0f*x); return 1.0f - 2.0f/(e + 1.0f); }

__device__ __forceinline__ f32x4 MFMA(us8 a, us8 b, f32x4 c){
  return __builtin_amdgcn_mfma_f32_16x16x32_bf16(
      __builtin_bit_cast(bf16x8, a), __builtin_bit_cast(bf16x8, b), c, 0, 0, 0);
}

struct SharedMem {
  unsigned short A0[2][NROW*A_STR];   // h0 state, bf16, double buffered (17408 B)
  unsigned short A1[2][NROW*A_STR];   // h1 state, bf16, double buffered (17408 B)
  unsigned short Ax[2][NROW][32];     // x-MFMA A operand                 (4096 B)
  unsigned short xw[512*8];           // x-MFMA B operand per gate-col    (8192 B)
  float c_lds[2][2][256][8];          // c-state [layer][rt][thr][ct*4+j] (32768 B)
  float b1[512];                      // bih1+bhh1 per col                (2048 B)
  float Wh2f[256];                    // Wh flattened                     (1024 B)
  float red[NROW][8][2];              // head partial sums                (2048 B)
  float we_s[64];
  float be_s[64];
  float bh_s[2];
};  // ~85.5 KB

// 256 threads = 4 waves = 1 wave/SIMD (geometric!), waves_per_eu(1,1)
// -> register budget 512/wave: 384 weight regs fit WITHOUT spill.
__global__ __launch_bounds__(256)
__attribute__((amdgpu_waves_per_eu(1, 1)))
void deepar_kernel(
    const float* __restrict__ hist, const float* __restrict__ fut,
    const float* __restrict__ We,   const float* __restrict__ be,
    const float* __restrict__ Wih0, const float* __restrict__ Whh0,
    const float* __restrict__ bih0, const float* __restrict__ bhh0,
    const float* __restrict__ Wih1, const float* __restrict__ Whh1,
    const float* __restrict__ bih1, const float* __restrict__ bhh1,
    const float* __restrict__ Wh,   const float* __restrict__ bh,
    float* __restrict__ out)
{
  __shared__ SharedMem S;
  const int tid = threadIdx.x;     // 0..255
  const int wg  = blockIdx.x;
  const int b   = wg / 10;
  const int n0  = (wg % 10) * NROW;
  const int w   = tid >> 6;        // wave 0..3
  const int l   = tid & 63;
  const int gq  = l >> 4;          // k-group 0..3
  const int r   = l & 15;          // row/col within 16-tile
  const int hbase = w * 32;        // h-col base of this wave (32 cols/wave)

  // ---------------- prologue: zero + param staging ----------------
  {
    us8 z = {0,0,0,0,0,0,0,0};
    us8* pA0 = (us8*)&S.A0[0][0];
    us8* pA1 = (us8*)&S.A1[0][0];
    for (int i = tid; i < 2*NROW*A_STR/8; i += 256){ pA0[i] = z; pA1[i] = z; }
    ((us8*)&S.Ax[0][0][0])[tid] = z;      // 2*32*32/8 == 256 chunks
    f32x4 zf = {0.f,0.f,0.f,0.f};
    #pragma unroll
    for (int q = 0; q < 8; ++q) *(f32x4*)&S.c_lds[q >> 2][(q >> 1) & 1][tid][(q & 1)*4] = zf;
  }
  S.Wh2f[tid] = Wh[tid];
  if (tid < 64)       S.we_s[tid]       = We[tid];
  else if (tid < 128) S.be_s[tid - 64]  = be[tid - 64];
  else if (tid < 130) S.bh_s[tid - 128] = bh[tid - 128];
  __syncthreads();

  // per-col x weights (2 cols per thread): u = Wih0[:,:64]@We ; v = ..@be + bih0 + bhh0
  for (int cc = tid; cc < 512; cc += 256){
    const float* wr = Wih0 + cc * 68;
    float u = 0.f, v = 0.f;
    #pragma unroll 8
    for (int e = 0; e < 64; ++e){
      float wv = wr[e];
      u = fmaf(wv, S.we_s[e], u);
      v = fmaf(wv, S.be_s[e], v);
    }
    v += bih0[cc] + bhh0[cc];
    unsigned short* xp = &S.xw[cc * 8];
    xp[0] = f2bf(u);
    xp[1] = f2bf(wr[64]); xp[2] = f2bf(wr[65]); xp[3] = f2bf(wr[66]); xp[4] = f2bf(wr[67]);
    xp[5] = f2bf(v);
    xp[6] = 0; xp[7] = 0;
    S.b1[cc] = bih1[cc] + bhh1[cc];
  }
  // Ax constant-one column (k=5), both buffers
  if (tid < 64){ int row = tid >> 1, bsel = tid & 1; S.Ax[bsel][row][5] = 0x3F80; }
  // stage step-0 scalars: tgt tau=0, cov tau=1 -> Ax[0]
  if (tid < 160){
    int srow, sch, tau;
    if (tid < 32){ srow = tid; sch = 0; tau = 0; }
    else { int k = tid - 32; srow = k >> 2; sch = 1 + (k & 3); tau = 1; }
    const float* p = hist + ((b*96 + tau)*320 + n0 + srow)*5;
    S.Ax[0][srow][sch] = f2bf(p[sch]);
  }

  // register-resident recurrent weights: WB[mat][gate][col-tile][kblock] = 96 frags = 384 regs
  us8 WB[3][4][2][4];
  #pragma unroll
  for (int m = 0; m < 3; ++m){
    const float* base = (m == 0) ? Whh0 : (m == 1) ? Wih1 : Whh1;
    #pragma unroll
    for (int g = 0; g < 4; ++g){
      #pragma unroll
      for (int ct = 0; ct < 2; ++ct){
        int col = g*128 + hbase + ct*16 + r;
        #pragma unroll
        for (int q = 0; q < 4; ++q){
          const float* p = base + col*128 + q*32 + gq*8;
          f32x4 x0 = *(const f32x4*)p;
          f32x4 x1 = *(const f32x4*)(p + 4);
          us8 tt;
          tt[0]=f2bf(x0[0]); tt[1]=f2bf(x0[1]); tt[2]=f2bf(x0[2]); tt[3]=f2bf(x0[3]);
          tt[4]=f2bf(x1[0]); tt[5]=f2bf(x1[1]); tt[6]=f2bf(x1[2]); tt[7]=f2bf(x1[3]);
          WB[m][g][ct][q] = tt;
        }
      }
    }
  }

  __syncthreads();

  // ---------------- time loop ----------------
  for (int t = 0; t < NSTEP; ++t){
    const int pb = t & 1, nb = pb ^ 1;
    const unsigned short* A0r = S.A0[pb];
    unsigned short*       A0w = S.A0[nb];
    const unsigned short* A1r = S.A1[pb];
    unsigned short*       A1w = S.A1[nb];

    // issue next-step scalar loads FIRST (hide HBM latency under both MFMA phases)
    float stv = 0.f; int sto = -1;
    if (t + 1 < NSTEP && tid < 160){
      int srow, sch, tau;
      if (tid < 32){ srow = tid; sch = 0; tau = t + 1; }
      else { int k = tid - 32; srow = k >> 2; sch = 1 + (k & 3); tau = t + 2; }
      const float* p = (tau < 96) ? (hist + ((b*96 + tau)*320 + n0 + srow)*5)
                                  : (fut  + ((b*24 + (tau - 96))*320 + n0 + srow)*5);
      stv = p[sch];
      sto = nb*NROW*32 + srow*32 + sch;
    }

    // ---- layer 0: gates = x-MFMA + h0 @ Whh0^T ; in-register activations ----
    #pragma unroll
    for (int rt = 0; rt < 2; ++rt){
      const int rbase = rt * 16;
      f32x4 acc[4][2];
      us8 ax = *(const us8*)&S.Ax[pb][rbase + r][gq*8];
      #pragma unroll
      for (int g = 0; g < 4; ++g)
        #pragma unroll
        for (int ct = 0; ct < 2; ++ct){
          us8 bx = *(const us8*)&S.xw[(g*128 + hbase + ct*16 + r)*8];
          f32x4 z = {0.f,0.f,0.f,0.f};
          acc[g][ct] = MFMA(ax, bx, z);
        }
      #pragma unroll
      for (int q = 0; q < 4; ++q){
        us8 a = *(const us8*)&A0r[(rbase + r)*A_STR + q*32 + gq*8];
        #pragma unroll
        for (int g = 0; g < 4; ++g)
          #pragma unroll
          for (int ct = 0; ct < 2; ++ct)
            acc[g][ct] = MFMA(a, WB[0][g][ct][q], acc[g][ct]);
      }
      f32x4 cpr[2], cn[2];
      cpr[0] = *(const f32x4*)&S.c_lds[0][rt][tid][0];
      cpr[1] = *(const f32x4*)&S.c_lds[0][rt][tid][4];
      #pragma unroll
      for (int ct = 0; ct < 2; ++ct)
        #pragma unroll
        for (int j = 0; j < 4; ++j){
          float c = fmaf(sigm(acc[1][ct][j]), cpr[ct][j],
                         sigm(acc[0][ct][j]) * tanh_(acc[2][ct][j]));
          cn[ct][j] = c;
          float h = sigm(acc[3][ct][j]) * tanh_(c);
          A0w[(rbase + gq*4 + j)*A_STR + hbase + ct*16 + r] = f2bf(h);
        }
      *(f32x4*)&S.c_lds[0][rt][tid][0] = cn[0];
      *(f32x4*)&S.c_lds[0][rt][tid][4] = cn[1];
    }
    __syncthreads();   // B1: new h0 visible

    // ---- layer 1: gates = b1 + h0new @ Wih1^T + h1 @ Whh1^T ----
    #pragma unroll
    for (int rt = 0; rt < 2; ++rt){
      const int rbase = rt * 16;
      f32x4 acc[4][2];
      #pragma unroll
      for (int g = 0; g < 4; ++g)
        #pragma unroll
        for (int ct = 0; ct < 2; ++ct){
          float bv = S.b1[g*128 + hbase + ct*16 + r];
          f32x4 iv = {bv, bv, bv, bv};
          acc[g][ct] = iv;
        }
      #pragma unroll
      for (int q = 0; q < 4; ++q){
        us8 a = *(const us8*)&A0w[(rbase + r)*A_STR + q*32 + gq*8];
        #pragma unroll
        for (int g = 0; g < 4; ++g)
          #pragma unroll
          for (int ct = 0; ct < 2; ++ct)
            acc[g][ct] = MFMA(a, WB[1][g][ct][q], acc[g][ct]);
      }
      #pragma unroll
      for (int q = 0; q < 4; ++q){
        us8 a = *(const us8*)&A1r[(rbase + r)*A_STR + q*32 + gq*8];
        #pragma unroll
        for (int g = 0; g < 4; ++g)
          #pragma unroll
          for (int ct = 0; ct < 2; ++ct)
            acc[g][ct] = MFMA(a, WB[2][g][ct][q], acc[g][ct]);
      }
      f32x4 cpr[2], cn[2];
      cpr[0] = *(const f32x4*)&S.c_lds[1][rt][tid][0];
      cpr[1] = *(const f32x4*)&S.c_lds[1][rt][tid][4];
      #pragma unroll
      for (int ct = 0; ct < 2; ++ct)
        #pragma unroll
        for (int j = 0; j < 4; ++j){
          float c = fmaf(sigm(acc[1][ct][j]), cpr[ct][j],
                         sigm(acc[0][ct][j]) * tanh_(acc[2][ct][j]));
          cn[ct][j] = c;
          float h = sigm(acc[3][ct][j]) * tanh_(c);
          A1w[(rbase + gq*4 + j)*A_STR + hbase + ct*16 + r] = f2bf(h);
        }
      *(f32x4*)&S.c_lds[1][rt][tid][0] = cn[0];
      *(f32x4*)&S.c_lds[1][rt][tid][4] = cn[1];
    }
    if (sto >= 0) ((unsigned short*)&S.Ax[0][0][0])[sto] = f2bf(stv);
    __syncthreads();   // B2: new h1 + next-step Ax visible

    // ---- head: only last 24 steps ----
    if (t >= 95){
      const int rown = tid >> 3, cg = tid & 7;   // each thread: 1 row x 16 h-cols
      us8 hv0 = *(const us8*)&A1w[rown*A_STR + cg*16];
      us8 hv1 = *(const us8*)&A1w[rown*A_STR + cg*16 + 8];
      float pm = 0.f, ps = 0.f;
      #pragma unroll
      for (int k = 0; k < 8; ++k){
        float ha = bf2f(hv0[k]); ha = ha > 0.f ? ha : 0.f;
        float hb = bf2f(hv1[k]); hb = hb > 0.f ? hb : 0.f;
        pm = fmaf(ha, S.Wh2f[cg*16 + k], pm);
        pm = fmaf(hb, S.Wh2f[cg*16 + 8 + k], pm);
        ps = fmaf(ha, S.Wh2f[128 + cg*16 + k], ps);
        ps = fmaf(hb, S.Wh2f[128 + cg*16 + 8 + k], ps);
      }
      S.red[rown][cg][0] = pm; S.red[rown][cg][1] = ps;
      __syncthreads(); // B3 (uniform: t is uniform)
      if (tid < 64){
        int row = tid >> 1, o = tid & 1;
        float s = S.bh_s[o];
        #pragma unroll
        for (int k = 0; k < 8; ++k) s += S.red[row][k][o];
        if (o) s = (s > 15.f) ? s : __logf(1.0f + __expf(s));
        out[((b*24 + (t - 95))*320 + (n0 + row))*2 + o] = s;
      }
    }
  }
}

extern "C" void kernel_launch(void* const* d_in, const int* in_sizes, int n_in,
                              void* d_out, int out_size, void* d_ws, size_t ws_size,
                              hipStream_t stream) {
  const float* hist = (const float*)d_in[0];
  const float* fut  = (const float*)d_in[1];
  const float* We   = (const float*)d_in[2];
  const float* be   = (const float*)d_in[3];
  const float* Wih0 = (const float*)d_in[4];
  const float* Whh0 = (const float*)d_in[5];
  const float* bih0 = (const float*)d_in[6];
  const float* bhh0 = (const float*)d_in[7];
  const float* Wih1 = (const float*)d_in[8];
  const float* Whh1 = (const float*)d_in[9];
  const float* bih1 = (const float*)d_in[10];
  const float* bhh1 = (const float*)d_in[11];
  const float* Wh   = (const float*)d_in[12];
  const float* bh   = (const float*)d_in[13];
  float* out = (float*)d_out;

  deepar_kernel<<<dim3(160), dim3(256), 0, stream>>>(
      hist, fut, We, be, Wih0, Whh0, bih0, bhh0,
      Wih1, Whh1, bih1, bhh1, Wh, bh, out);
}

// Round 7
// 1108.643 us; speedup vs baseline: 1.2974x; 1.2974x over previous
//
#include <hip/hip_runtime.h>

typedef __bf16 bf16x8 __attribute__((ext_vector_type(8)));
typedef unsigned short us8 __attribute__((ext_vector_type(8)));
typedef float f32x4 __attribute__((ext_vector_type(4)));

#define NROW 32      // rows per workgroup (160 WGs x 32 = 5120)
#define A_STR 136    // ushort stride per A row (b128 frag reads land perfectly balanced: 8 cyc/wave)
#define NSTEP 119

__device__ __forceinline__ unsigned short f2bf(float f){
  unsigned int x = __builtin_bit_cast(unsigned int, f);
  x += 0x7fffu + ((x >> 16) & 1u);          // RNE
  return (unsigned short)(x >> 16);
}
__device__ __forceinline__ float bf2f(unsigned short s){
  unsigned int x = ((unsigned int)s) << 16;
  return __builtin_bit_cast(float, x);
}
__device__ __forceinline__ float sigm(float x){ return 1.0f/(1.0f + __expf(-x)); }
__device__ __forceinline__ float tanh_(float x){ float e = __expf(2.0f*x); return 1.0f - 2.0f/(e + 1.0f); }

__device__ __forceinline__ f32x4 MFMA(us8 a, us8 b, f32x4 c){
  return __builtin_amdgcn_mfma_f32_16x16x32_bf16(
      __builtin_bit_cast(bf16x8, a), __builtin_bit_cast(bf16x8, b), c, 0, 0, 0);
}

// AGPR-resident weight path: "a" constraint forces the B fragment into the
// accumulator file (256 regs that the arch-VGPR allocator cannot reach).
// Copies in (v_accvgpr_write) are loop-invariant -> prologue.
__device__ __forceinline__ void mfma_ag_first(f32x4& d, us8 a, us8 b){
  // s_nop guards VALU-write(acc init) -> MFMA srcC read hazard (asm is opaque
  // to the hazard recognizer)
  asm("s_nop 1\n\tv_mfma_f32_16x16x32_bf16 %0, %1, %2, %0" : "+v"(d) : "v"(a), "a"(b));
}
__device__ __forceinline__ void mfma_ag(f32x4& d, us8 a, us8 b){
  asm("v_mfma_f32_16x16x32_bf16 %0, %1, %2, %0" : "+v"(d) : "v"(a), "a"(b));
}
// fence before VALU reads accumulators (MFMA D -> VALU read hazard):
// routing all 8 accs through "+v" orders all later reads after the nops.
__device__ __forceinline__ void accfence8(f32x4& a0, f32x4& a1, f32x4& a2, f32x4& a3,
                                          f32x4& a4, f32x4& a5, f32x4& a6, f32x4& a7){
  asm("s_nop 7\n\ts_nop 7\n\ts_nop 2"
      : "+v"(a0), "+v"(a1), "+v"(a2), "+v"(a3),
        "+v"(a4), "+v"(a5), "+v"(a6), "+v"(a7));
}

struct SharedMem {
  unsigned short A0[2][NROW*A_STR];   // h0 state, bf16, double buffered (17408 B)
  unsigned short A1[2][NROW*A_STR];   // h1 state, bf16, double buffered (17408 B)
  unsigned short Ax[2][NROW][32];     // x-MFMA A operand                 (4096 B)
  unsigned short xw[512*8];           // x-MFMA B operand per gate-col    (8192 B)
  float c_lds[2][2][2][256][4];       // c [layer][rt][ct][thr][j] 16B/lane (32768 B)
  float b1[512];                      // bih1+bhh1 per col                (2048 B)
  float Wh2f[256];                    // Wh flattened                     (1024 B)
  float red[NROW][8][2];              // head partial sums                (2048 B)
  float we_s[64];
  float be_s[64];
  float bh_s[2];
};  // ~86 KB -> 1 WG/CU

// 256 threads = 4 waves = 1 wave/SIMD; waves_per_eu(1,1) -> 512-reg unified
// budget/wave: 256 arch VGPR + 256 AGPR. Weights: 128 VGPR + 256 AGPR.
__global__ __launch_bounds__(256)
__attribute__((amdgpu_waves_per_eu(1, 1)))
void deepar_kernel(
    const float* __restrict__ hist, const float* __restrict__ fut,
    const float* __restrict__ We,   const float* __restrict__ be,
    const float* __restrict__ Wih0, const float* __restrict__ Whh0,
    const float* __restrict__ bih0, const float* __restrict__ bhh0,
    const float* __restrict__ Wih1, const float* __restrict__ Whh1,
    const float* __restrict__ bih1, const float* __restrict__ bhh1,
    const float* __restrict__ Wh,   const float* __restrict__ bh,
    float* __restrict__ out)
{
  __shared__ SharedMem S;
  const int tid = threadIdx.x;     // 0..255
  const int wg  = blockIdx.x;
  const int b   = wg / 10;
  const int n0  = (wg % 10) * NROW;
  const int w   = tid >> 6;        // wave 0..3
  const int l   = tid & 63;
  const int gq  = l >> 4;          // k-group 0..3
  const int r   = l & 15;          // row/col within 16-tile
  const int hbase = w * 32;        // h-col base of this wave (32 cols/wave)

  // ---------------- prologue: zero + param staging ----------------
  {
    us8 z = {0,0,0,0,0,0,0,0};
    us8* pA0 = (us8*)&S.A0[0][0];
    us8* pA1 = (us8*)&S.A1[0][0];
    for (int i = tid; i < 2*NROW*A_STR/8; i += 256){ pA0[i] = z; pA1[i] = z; }
    ((us8*)&S.Ax[0][0][0])[tid] = z;      // 2*32*32/8 == 256 chunks
    f32x4 zf = {0.f,0.f,0.f,0.f};
    #pragma unroll
    for (int q = 0; q < 8; ++q) *(f32x4*)&S.c_lds[q >> 2][(q >> 1) & 1][q & 1][tid][0] = zf;
  }
  S.Wh2f[tid] = Wh[tid];
  if (tid < 64)       S.we_s[tid]       = We[tid];
  else if (tid < 128) S.be_s[tid - 64]  = be[tid - 64];
  else if (tid < 130) S.bh_s[tid - 128] = bh[tid - 128];
  __syncthreads();

  // per-col x weights (2 cols per thread): u = Wih0[:,:64]@We ; v = ..@be + bih0 + bhh0
  for (int cc = tid; cc < 512; cc += 256){
    const float* wr = Wih0 + cc * 68;
    float u = 0.f, v = 0.f;
    #pragma unroll 8
    for (int e = 0; e < 64; ++e){
      float wv = wr[e];
      u = fmaf(wv, S.we_s[e], u);
      v = fmaf(wv, S.be_s[e], v);
    }
    v += bih0[cc] + bhh0[cc];
    unsigned short* xp = &S.xw[cc * 8];
    xp[0] = f2bf(u);
    xp[1] = f2bf(wr[64]); xp[2] = f2bf(wr[65]); xp[3] = f2bf(wr[66]); xp[4] = f2bf(wr[67]);
    xp[5] = f2bf(v);
    xp[6] = 0; xp[7] = 0;
    S.b1[cc] = bih1[cc] + bhh1[cc];
  }
  // Ax constant-one column (k=5), both buffers
  if (tid < 64){ int row = tid >> 1, bsel = tid & 1; S.Ax[bsel][row][5] = 0x3F80; }
  // stage step-0 scalars: tgt tau=0, cov tau=1 -> Ax[0]
  if (tid < 160){
    int srow, sch, tau;
    if (tid < 32){ srow = tid; sch = 0; tau = 0; }
    else { int k = tid - 32; srow = k >> 2; sch = 1 + (k & 3); tau = 1; }
    const float* p = hist + ((b*96 + tau)*320 + n0 + srow)*5;
    S.Ax[0][srow][sch] = f2bf(p[sch]);
  }

  // weight fragments: WV (Whh0) -> VGPR/intrinsic; WA1 (Wih1), WA2 (Whh1) -> AGPR/asm
  us8 WV[4][2][4], WA1[4][2][4], WA2[4][2][4];
  #pragma unroll
  for (int m = 0; m < 3; ++m){
    const float* base = (m == 0) ? Whh0 : (m == 1) ? Wih1 : Whh1;
    #pragma unroll
    for (int g = 0; g < 4; ++g){
      #pragma unroll
      for (int ct = 0; ct < 2; ++ct){
        int col = g*128 + hbase + ct*16 + r;
        #pragma unroll
        for (int q = 0; q < 4; ++q){
          const float* p = base + col*128 + q*32 + gq*8;
          f32x4 x0 = *(const f32x4*)p;
          f32x4 x1 = *(const f32x4*)(p + 4);
          us8 tt;
          tt[0]=f2bf(x0[0]); tt[1]=f2bf(x0[1]); tt[2]=f2bf(x0[2]); tt[3]=f2bf(x0[3]);
          tt[4]=f2bf(x1[0]); tt[5]=f2bf(x1[1]); tt[6]=f2bf(x1[2]); tt[7]=f2bf(x1[3]);
          if (m == 0) WV[g][ct][q]  = tt;
          else if (m == 1) WA1[g][ct][q] = tt;
          else WA2[g][ct][q] = tt;
        }
      }
    }
  }

  __syncthreads();

  // ---------------- time loop ----------------
  for (int t = 0; t < NSTEP; ++t){
    const int pb = t & 1, nb = pb ^ 1;
    const unsigned short* A0r = S.A0[pb];
    unsigned short*       A0w = S.A0[nb];
    const unsigned short* A1r = S.A1[pb];
    unsigned short*       A1w = S.A1[nb];

    // issue next-step scalar loads FIRST (hide HBM latency under both MFMA phases)
    float stv = 0.f; int sto = -1;
    if (t + 1 < NSTEP && tid < 160){
      int srow, sch, tau;
      if (tid < 32){ srow = tid; sch = 0; tau = t + 1; }
      else { int k = tid - 32; srow = k >> 2; sch = 1 + (k & 3); tau = t + 2; }
      const float* p = (tau < 96) ? (hist + ((b*96 + tau)*320 + n0 + srow)*5)
                                  : (fut  + ((b*24 + (tau - 96))*320 + n0 + srow)*5);
      stv = p[sch];
      sto = nb*NROW*32 + srow*32 + sch;
    }

    // ---- layer 0 (all-intrinsic): gates = x-MFMA + h0 @ Whh0^T ----
    #pragma unroll
    for (int rt = 0; rt < 2; ++rt){
      const int rbase = rt * 16;
      f32x4 acc[4][2];
      us8 ax = *(const us8*)&S.Ax[pb][rbase + r][gq*8];
      #pragma unroll
      for (int g = 0; g < 4; ++g)
        #pragma unroll
        for (int ct = 0; ct < 2; ++ct){
          us8 bx = *(const us8*)&S.xw[(g*128 + hbase + ct*16 + r)*8];
          f32x4 z = {0.f,0.f,0.f,0.f};
          acc[g][ct] = MFMA(ax, bx, z);
        }
      #pragma unroll
      for (int q = 0; q < 4; ++q){
        us8 a = *(const us8*)&A0r[(rbase + r)*A_STR + q*32 + gq*8];
        #pragma unroll
        for (int g = 0; g < 4; ++g)
          #pragma unroll
          for (int ct = 0; ct < 2; ++ct)
            acc[g][ct] = MFMA(a, WV[g][ct][q], acc[g][ct]);
      }
      f32x4 cpr[2], cn[2];
      cpr[0] = *(const f32x4*)&S.c_lds[0][rt][0][tid][0];
      cpr[1] = *(const f32x4*)&S.c_lds[0][rt][1][tid][0];
      #pragma unroll
      for (int ct = 0; ct < 2; ++ct)
        #pragma unroll
        for (int j = 0; j < 4; ++j){
          float c = fmaf(sigm(acc[1][ct][j]), cpr[ct][j],
                         sigm(acc[0][ct][j]) * tanh_(acc[2][ct][j]));
          cn[ct][j] = c;
          float h = sigm(acc[3][ct][j]) * tanh_(c);
          A0w[(rbase + gq*4 + j)*A_STR + hbase + ct*16 + r] = f2bf(h);
        }
      *(f32x4*)&S.c_lds[0][rt][0][tid][0] = cn[0];
      *(f32x4*)&S.c_lds[0][rt][1][tid][0] = cn[1];
    }
    __syncthreads();   // B1: new h0 visible

    // ---- layer 1 (AGPR asm): gates = b1 + h0new @ Wih1^T + h1 @ Whh1^T ----
    #pragma unroll
    for (int rt = 0; rt < 2; ++rt){
      const int rbase = rt * 16;
      f32x4 acc[4][2];
      #pragma unroll
      for (int g = 0; g < 4; ++g)
        #pragma unroll
        for (int ct = 0; ct < 2; ++ct){
          float bv = S.b1[g*128 + hbase + ct*16 + r];
          f32x4 iv = {bv, bv, bv, bv};
          acc[g][ct] = iv;
        }
      {
        us8 a = *(const us8*)&A0w[(rbase + r)*A_STR + 0*32 + gq*8];
        #pragma unroll
        for (int g = 0; g < 4; ++g)
          #pragma unroll
          for (int ct = 0; ct < 2; ++ct)
            mfma_ag_first(acc[g][ct], a, WA1[g][ct][0]);
      }
      #pragma unroll
      for (int q = 1; q < 4; ++q){
        us8 a = *(const us8*)&A0w[(rbase + r)*A_STR + q*32 + gq*8];
        #pragma unroll
        for (int g = 0; g < 4; ++g)
          #pragma unroll
          for (int ct = 0; ct < 2; ++ct)
            mfma_ag(acc[g][ct], a, WA1[g][ct][q]);
      }
      #pragma unroll
      for (int q = 0; q < 4; ++q){
        us8 a = *(const us8*)&A1r[(rbase + r)*A_STR + q*32 + gq*8];
        #pragma unroll
        for (int g = 0; g < 4; ++g)
          #pragma unroll
          for (int ct = 0; ct < 2; ++ct)
            mfma_ag(acc[g][ct], a, WA2[g][ct][q]);
      }
      accfence8(acc[0][0], acc[0][1], acc[1][0], acc[1][1],
                acc[2][0], acc[2][1], acc[3][0], acc[3][1]);
      f32x4 cpr[2], cn[2];
      cpr[0] = *(const f32x4*)&S.c_lds[1][rt][0][tid][0];
      cpr[1] = *(const f32x4*)&S.c_lds[1][rt][1][tid][0];
      #pragma unroll
      for (int ct = 0; ct < 2; ++ct)
        #pragma unroll
        for (int j = 0; j < 4; ++j){
          float c = fmaf(sigm(acc[1][ct][j]), cpr[ct][j],
                         sigm(acc[0][ct][j]) * tanh_(acc[2][ct][j]));
          cn[ct][j] = c;
          float h = sigm(acc[3][ct][j]) * tanh_(c);
          A1w[(rbase + gq*4 + j)*A_STR + hbase + ct*16 + r] = f2bf(h);
        }
      *(f32x4*)&S.c_lds[1][rt][0][tid][0] = cn[0];
      *(f32x4*)&S.c_lds[1][rt][1][tid][0] = cn[1];
    }
    if (sto >= 0) ((unsigned short*)&S.Ax[0][0][0])[sto] = f2bf(stv);
    __syncthreads();   // B2: new h1 + next-step Ax visible

    // ---- head: only last 24 steps ----
    if (t >= 95){
      const int rown = tid >> 3, cg = tid & 7;   // each thread: 1 row x 16 h-cols
      us8 hv0 = *(const us8*)&A1w[rown*A_STR + cg*16];
      us8 hv1 = *(const us8*)&A1w[rown*A_STR + cg*16 + 8];
      float pm = 0.f, ps = 0.f;
      #pragma unroll
      for (int k = 0; k < 8; ++k){
        float ha = bf2f(hv0[k]); ha = ha > 0.f ? ha : 0.f;
        float hb = bf2f(hv1[k]); hb = hb > 0.f ? hb : 0.f;
        pm = fmaf(ha, S.Wh2f[cg*16 + k], pm);
        pm = fmaf(hb, S.Wh2f[cg*16 + 8 + k], pm);
        ps = fmaf(ha, S.Wh2f[128 + cg*16 + k], ps);
        ps = fmaf(hb, S.Wh2f[128 + cg*16 + 8 + k], ps);
      }
      S.red[rown][cg][0] = pm; S.red[rown][cg][1] = ps;
      __syncthreads(); // B3 (uniform: t is uniform)
      if (tid < 64){
        int row = tid >> 1, o = tid & 1;
        float s = S.bh_s[o];
        #pragma unroll
        for (int k = 0; k < 8; ++k) s += S.red[row][k][o];
        if (o) s = (s > 15.f) ? s : __logf(1.0f + __expf(s));
        out[((b*24 + (t - 95))*320 + (n0 + row))*2 + o] = s;
      }
    }
  }
}

extern "C" void kernel_launch(void* const* d_in, const int* in_sizes, int n_in,
                              void* d_out, int out_size, void* d_ws, size_t ws_size,
                              hipStream_t stream) {
  const float* hist = (const float*)d_in[0];
  const float* fut  = (const float*)d_in[1];
  const float* We   = (const float*)d_in[2];
  const float* be   = (const float*)d_in[3];
  const float* Wih0 = (const float*)d_in[4];
  const float* Whh0 = (const float*)d_in[5];
  const float* bih0 = (const float*)d_in[6];
  const float* bhh0 = (const float*)d_in[7];
  const float* Wih1 = (const float*)d_in[8];
  const float* Whh1 = (const float*)d_in[9];
  const float* bih1 = (const float*)d_in[10];
  const float* bhh1 = (const float*)d_in[11];
  const float* Wh   = (const float*)d_in[12];
  const float* bh   = (const float*)d_in[13];
  float* out = (float*)d_out;

  deepar_kernel<<<dim3(160), dim3(256), 0, stream>>>(
      hist, fut, We, be, Wih0, Whh0, bih0, bhh0,
      Wih1, Whh1, bih1, bhh1, Wh, bh, out);
}